// Round 18
// baseline (714.234 us; speedup 1.0000x reference)
//
#include <hip/hip_runtime.h>
#include <hip/hip_bf16.h>
#include <math.h>

// B=4, M=2048, D=512, H=8. Heads in groups of G (G=4 on this harness).

typedef __attribute__((ext_vector_type(8))) __bf16 bf16x8;
typedef __attribute__((ext_vector_type(4))) __bf16 bf16x4;
typedef __attribute__((ext_vector_type(4))) float f32x4;

#define MFMA16(a, b, c) __builtin_amdgcn_mfma_f32_16x16x32_bf16((a), (b), (c), 0, 0, 0)

__device__ __forceinline__ void g2l16(const void* g, void* l) {
  __builtin_amdgcn_global_load_lds((const __attribute__((address_space(1))) void*)g,
                                   (__attribute__((address_space(3))) void*)l, 16, 0, 0);
}

// ---------------- fused prep: all fp32->bf16 casts + RoPE tables ----------------
__global__ void prep_k(const float* __restrict__ x, const float* __restrict__ wq,
                       const float* __restrict__ wk, const float* __restrict__ wv,
                       const float* __restrict__ wo,
                       __bf16* __restrict__ xb, __bf16* __restrict__ wqb,
                       __bf16* __restrict__ wkb, __bf16* __restrict__ wvb,
                       __bf16* __restrict__ wob,
                       float* __restrict__ ct, float* __restrict__ st) {
  int i = blockIdx.x * 256 + threadIdx.x;
  if (i < 3145728) {
    const float* src;
    __bf16* dst;
    int off = i;
    if (i < 1048576) { src = x; dst = xb; }
    else if (i < 1572864) { src = wq; dst = wqb; off = i - 1048576; }
    else if (i < 2097152) { src = wk; dst = wkb; off = i - 1572864; }
    else if (i < 2621440) { src = wv; dst = wvb; off = i - 2097152; }
    else { src = wo; dst = wob; off = i - 2621440; }
    float4 f = reinterpret_cast<const float4*>(src)[off];
    bf16x4 o;
    o.x = (__bf16)f.x; o.y = (__bf16)f.y; o.z = (__bf16)f.z; o.w = (__bf16)f.w;
    reinterpret_cast<bf16x4*>(dst)[off] = o;
  } else {
    int idx = i - 3145728;  // 2048*256
    int m = idx >> 8, j = idx & 255;
    float e = (-2.0f * ((float)j - 1.0f) / 512.0f) * 13.287712379549449f;  // log2(1e4)
    float theta = exp2f(e);
    float ang = (float)m * theta;
    float s, c;
    sincosf(ang, &s, &c);
    ct[idx] = c;
    st[idx] = s;
  }
}

// ---------------- QKV projection: z = which*G + hl; V written directly transposed ----------------
__global__ __launch_bounds__(256, 2) void qkv_gemm_k(
    const __bf16* __restrict__ Xb,
    const __bf16* __restrict__ Wqb, const __bf16* __restrict__ Wkb, const __bf16* __restrict__ Wvb,
    const float* __restrict__ ct, const float* __restrict__ st,
    __bf16* __restrict__ Q, __bf16* __restrict__ K, __bf16* __restrict__ VT,
    int G, int lg, int h0) {
  const int z = blockIdx.z;
  const int which = z >> lg, hl = z & (G - 1);
  const int h = h0 + hl;
  const __bf16* W = (which == 0 ? Wqb : which == 1 ? Wkb : Wvb) + (size_t)h * 262144;

  const int mbase = blockIdx.x * 128;
  const int nbase = blockIdx.y * 128;

  __shared__ alignas(16) __bf16 As[128 * 64];
  __shared__ alignas(16) __bf16 Bs[128 * 64];

  const int tid = threadIdx.x;
  const int lane = tid & 63, wid = tid >> 6;
  const int wr = wid >> 1, wc = wid & 1;
  const int l15 = lane & 15, l4 = lane >> 4;

  f32x4 acc[4][4];
#pragma unroll
  for (int i = 0; i < 4; i++)
#pragma unroll
    for (int j = 0; j < 4; j++) acc[i][j] = f32x4{0.f, 0.f, 0.f, 0.f};

  for (int kt = 0; kt < 8; ++kt) {
    const int kb = kt * 64;
#pragma unroll
    for (int i = 0; i < 4; i++) {
      int chunk = i * 256 + tid;
      int row = chunk >> 3, col = (chunk & 7) * 8;
      g2l16(Xb + (size_t)(mbase + row) * 512 + kb + col, As + (i * 256 + (tid & ~63)) * 8);
    }
#pragma unroll
    for (int i = 0; i < 4; i++) {
      int chunk = i * 256 + tid;
      int row = chunk >> 3, col = (chunk & 7) * 8;
      g2l16(W + (size_t)(nbase + row) * 512 + kb + col, Bs + (i * 256 + (tid & ~63)) * 8);
    }
    __syncthreads();
#pragma unroll
    for (int kk = 0; kk < 2; ++kk) {
      bf16x8 a[4], b[4];
#pragma unroll
      for (int i = 0; i < 4; i++)
        a[i] = *reinterpret_cast<const bf16x8*>(As + (wr * 64 + i * 16 + l15) * 64 + kk * 32 + l4 * 8);
#pragma unroll
      for (int j = 0; j < 4; j++)
        b[j] = *reinterpret_cast<const bf16x8*>(Bs + (wc * 64 + j * 16 + l15) * 64 + kk * 32 + l4 * 8);
#pragma unroll
      for (int i = 0; i < 4; i++)
#pragma unroll
        for (int j = 0; j < 4; j++) acc[i][j] = MFMA16(a[i], b[j], acc[i][j]);
    }
    __syncthreads();
  }

  if (which == 2) {
    const int b_ = mbase >> 11;
    const int mloc = mbase & 2047;
    __bf16* Tgw = VT + (size_t)(b_ * G + hl) * 512 * 2048;
#pragma unroll
    for (int i = 0; i < 4; i++) {
#pragma unroll
      for (int j = 0; j < 4; j++) {
        const int col = nbase + wc * 64 + j * 16 + l15;
        const int m0 = mloc + wr * 64 + i * 16 + l4 * 4;
        bf16x4 pk;
        pk.x = (__bf16)acc[i][j][0];
        pk.y = (__bf16)acc[i][j][1];
        pk.z = (__bf16)acc[i][j][2];
        pk.w = (__bf16)acc[i][j][3];
        *reinterpret_cast<bf16x4*>(&Tgw[(size_t)col * 2048 + m0]) = pk;
      }
    }
  } else {
    __bf16* Out = which ? K : Q;
#pragma unroll
    for (int i = 0; i < 4; i++) {
#pragma unroll
      for (int j = 0; j < 4; j++) {
        const int col = nbase + wc * 64 + j * 16 + l15;
#pragma unroll
        for (int r = 0; r < 4; r++) {
          const int rowg = mbase + wr * 64 + i * 16 + l4 * 4 + r;
          const int b_ = rowg >> 11, m = rowg & 2047;
          float v = acc[i][j][r];
          float pv = __shfl_xor(v, 1, 64);
          float c = ct[m * 256 + (col >> 1)];
          float s = st[m * 256 + (col >> 1)];
          v = (col & 1) ? (v * c - pv * s) : (v * c + pv * s);
          Out[(size_t)((b_ * G + hl) * 2048 + m) * 512 + col] = (__bf16)v;
        }
      }
    }
  }
}

// ---------------- non-split fallback flash (R10/R14 proven) ----------------
__global__ __launch_bounds__(512) void flash_attn_k(
    const __bf16* __restrict__ Q, const __bf16* __restrict__ K, const __bf16* __restrict__ VT,
    __bf16* __restrict__ O0, int G, int lg) {
  const int bhN = 4 * G;
  const int L = blockIdx.x + 16 * blockIdx.y;
  const int half = L / (8 * bhN);
  const int r_ = L % (8 * bhN);
  const int bh = r_ % bhN;
  const int p_ = r_ / bhN;
  const int qblk = half ? (15 - p_) : p_;
  const int b = bh >> lg, hl = bh & (G - 1);
  const int tid = threadIdx.x, lane = tid & 63, wid = tid >> 6;
  const int l15 = lane & 15, l4 = lane >> 4;
  const int qw = qblk * 128 + wid * 16;

  __shared__ alignas(16) __bf16 Ks[32 * 512];
  __shared__ alignas(16) __bf16 Vts[512 * 32];
  __shared__ alignas(16) __bf16 Ps[8][16 * 32];

  const __bf16* Qg = Q + ((size_t)bh * 2048 + qw) * 512;
  const __bf16* Kg = K + (size_t)bh * 2048 * 512;
  const __bf16* Tg = VT + (size_t)bh * 512 * 2048;

  bf16x8 qf[16];
#pragma unroll
  for (int c = 0; c < 16; c++)
    qf[c] = *reinterpret_cast<const bf16x8*>(Qg + l15 * 512 + c * 32 + l4 * 8);

  f32x4 acc[32];
#pragma unroll
  for (int n = 0; n < 32; n++) acc[n] = f32x4{0.f, 0.f, 0.f, 0.f};
  float mrow[4] = {-INFINITY, -INFINITY, -INFINITY, -INFINITY};
  float lrow[4] = {0.f, 0.f, 0.f, 0.f};

  const float scale = 0.04419417382415922f;
  const int ntiles = qblk * 4 + 4;

  for (int kt = 0; kt < ntiles; ++kt) {
    const int kb = kt * 32;
#pragma unroll
    for (int i = 0; i < 4; i++) {
      int chunk = i * 512 + tid;
      int row = chunk >> 6, c16 = chunk & 63;
      g2l16(Kg + (size_t)(kb + row) * 512 + ((c16 ^ (row & 7)) << 3),
            Ks + (i * 512 + (tid & ~63)) * 8);
    }
#pragma unroll
    for (int i = 0; i < 4; i++) {
      int chunk = i * 512 + tid;
      int row = chunk >> 2, c4 = chunk & 3;
      g2l16(Tg + (size_t)row * 2048 + kb + ((c4 ^ ((row >> 1) & 3)) << 3),
            Vts + (i * 512 + (tid & ~63)) * 8);
    }
    __syncthreads();

    f32x4 sv0 = f32x4{0.f, 0.f, 0.f, 0.f}, sv1 = f32x4{0.f, 0.f, 0.f, 0.f};
#pragma unroll
    for (int c = 0; c < 16; c++) {
      const int off = c * 32 + l4 * 8;
      const int r0 = l15, r1 = 16 + l15;
      bf16x8 b0 = *reinterpret_cast<const bf16x8*>(Ks + r0 * 512 + (off ^ ((r0 & 7) << 3)));
      bf16x8 b1 = *reinterpret_cast<const bf16x8*>(Ks + r1 * 512 + (off ^ ((r1 & 7) << 3)));
      sv0 = MFMA16(qf[c], b0, sv0);
      sv1 = MFMA16(qf[c], b1, sv1);
    }

    float mx[4];
#pragma unroll
    for (int r = 0; r < 4; r++) {
      const int qg = qw + l4 * 4 + r;
      float s0 = sv0[r] * scale;
      float s1 = sv1[r] * scale;
      if (kb + l15 > qg) s0 = -INFINITY;
      if (kb + 16 + l15 > qg) s1 = -INFINITY;
      sv0[r] = s0; sv1[r] = s1;
      float m_ = fmaxf(s0, s1);
      m_ = fmaxf(m_, __shfl_xor(m_, 1, 64));
      m_ = fmaxf(m_, __shfl_xor(m_, 2, 64));
      m_ = fmaxf(m_, __shfl_xor(m_, 4, 64));
      m_ = fmaxf(m_, __shfl_xor(m_, 8, 64));
      mx[r] = m_;
    }
    bool need = (mx[0] > mrow[0] + 8.f) || (mx[1] > mrow[1] + 8.f) ||
                (mx[2] > mrow[2] + 8.f) || (mx[3] > mrow[3] + 8.f);
    if (__any(need)) {
      float alpha[4];
#pragma unroll
      for (int r = 0; r < 4; r++) {
        float mn = fmaxf(mrow[r], mx[r]);
        alpha[r] = __expf(mrow[r] - mn);
        lrow[r] *= alpha[r];
        mrow[r] = mn;
      }
#pragma unroll
      for (int n = 0; n < 32; n++) {
#pragma unroll
        for (int r = 0; r < 4; r++) acc[n][r] *= alpha[r];
      }
    }
#pragma unroll
    for (int r = 0; r < 4; r++) {
      float p0 = __expf(sv0[r] - mrow[r]);
      float p1 = __expf(sv1[r] - mrow[r]);
      float rs = p0 + p1;
      rs += __shfl_xor(rs, 1, 64);
      rs += __shfl_xor(rs, 2, 64);
      rs += __shfl_xor(rs, 4, 64);
      rs += __shfl_xor(rs, 8, 64);
      lrow[r] += rs;
      __bf16* P = &Ps[wid][0];
      P[(l4 * 4 + r) * 32 + l15] = (__bf16)p0;
      P[(l4 * 4 + r) * 32 + 16 + l15] = (__bf16)p1;
    }
    bf16x8 pf = *reinterpret_cast<const bf16x8*>(&Ps[wid][0] + l15 * 32 + l4 * 8);
#pragma unroll
    for (int n = 0; n < 32; n++) {
      const int row = n * 16 + l15;
      bf16x8 vb = *reinterpret_cast<const bf16x8*>(Vts + row * 32 + ((l4 * 8) ^ (((row >> 1) & 3) << 3)));
      acc[n] = MFMA16(pf, vb, acc[n]);
    }
    __syncthreads();
  }

#pragma unroll
  for (int r = 0; r < 4; r++) {
    const int qg = qw + l4 * 4 + r;
    const float inv = 1.0f / lrow[r];
    __bf16* Og = O0 + ((size_t)(b * 2048 + qg) * (512 * G) + hl * 512);
#pragma unroll
    for (int n = 0; n < 32; n++) Og[n * 16 + l15] = (__bf16)(acc[n][r] * inv);
  }
}

// ---------------- flashB: split-K, 2-barrier drain-covered schedule, padded Ps ----------------
// NaN-safety: mrow init -1e30 (finite) so fully-masked rows give P=exp(-inf)=0, not NaN;
// epilogue inv guarded so empty partials store exact zeros.
__global__ __launch_bounds__(512) void flashB_k(
    const __bf16* __restrict__ Q, const __bf16* __restrict__ K, const __bf16* __restrict__ VT,
    __bf16* __restrict__ O0, __bf16* __restrict__ O1, float2* __restrict__ Ml,
    int G, int lg) {
  const int bhN = 4 * G;
  const int L = blockIdx.x;
  const int bh = L % bhN;
  const int s_ = L / bhN;  // 0..31
  const int ks = (s_ < 16) ? 0 : 1;
  const int qblk = ks ? (31 - s_) : s_;
  const int hn = 2 * qblk + 2;
  const int kt0 = ks * hn, kt1 = kt0 + hn;
  const int b = bh >> lg, hl = bh & (G - 1);
  const int tid = threadIdx.x, lane = tid & 63, wid = tid >> 6;
  const int l15 = lane & 15, l4 = lane >> 4;
  const int qw = qblk * 128 + wid * 16;

  __shared__ alignas(16) __bf16 Ks[32 * 512];
  __shared__ alignas(16) __bf16 Vts[512 * 32];
  __shared__ alignas(16) __bf16 Ps[8][16 * 40];  // stride 40: aligned + write-conflict-free

  const __bf16* Qg = Q + ((size_t)bh * 2048 + qw) * 512;
  const __bf16* Kg = K + (size_t)bh * 2048 * 512;
  const __bf16* Tg = VT + (size_t)bh * 512 * 2048;

  bf16x8 qf[16];
#pragma unroll
  for (int c = 0; c < 16; c++)
    qf[c] = *reinterpret_cast<const bf16x8*>(Qg + l15 * 512 + c * 32 + l4 * 8);

  f32x4 acc[32];
#pragma unroll
  for (int n = 0; n < 32; n++) acc[n] = f32x4{0.f, 0.f, 0.f, 0.f};
  float mrow[4] = {-1e30f, -1e30f, -1e30f, -1e30f};  // finite: masked rows stay NaN-free
  float lrow[4] = {0.f, 0.f, 0.f, 0.f};

  const float scale = 0.04419417382415922f;

  auto stageK = [&](int kt2) {
#pragma unroll
    for (int i = 0; i < 4; i++) {
      int chunk = i * 512 + tid;
      int row = chunk >> 6, c16 = chunk & 63;
      g2l16(Kg + (size_t)(kt2 * 32 + row) * 512 + ((c16 ^ (row & 7)) << 3),
            Ks + (i * 512 + (tid & ~63)) * 8);
    }
  };
  auto stageV = [&](int kt2) {
#pragma unroll
    for (int i = 0; i < 4; i++) {
      int chunk = i * 512 + tid;
      int row = chunk >> 2, c4 = chunk & 3;
      g2l16(Tg + (size_t)row * 2048 + kt2 * 32 + ((c4 ^ ((row >> 1) & 3)) << 3),
            Vts + (i * 512 + (tid & ~63)) * 8);
    }
  };

  stageK(kt0);

  for (int kt = kt0; kt < kt1; ++kt) {
    const int kb = kt * 32;
    __syncthreads();  // barrier1: PV(kt-1) done; drains K(kt) (covered by prev PV)
    stageV(kt);       // flies under QK + softmax

    f32x4 sv0 = f32x4{0.f, 0.f, 0.f, 0.f}, sv1 = f32x4{0.f, 0.f, 0.f, 0.f};
#pragma unroll
    for (int c = 0; c < 16; c++) {
      const int off = c * 32 + l4 * 8;
      const int r0 = l15, r1 = 16 + l15;
      bf16x8 b0 = *reinterpret_cast<const bf16x8*>(Ks + r0 * 512 + (off ^ ((r0 & 7) << 3)));
      bf16x8 b1 = *reinterpret_cast<const bf16x8*>(Ks + r1 * 512 + (off ^ ((r1 & 7) << 3)));
      sv0 = MFMA16(qf[c], b0, sv0);
      sv1 = MFMA16(qf[c], b1, sv1);
    }

    float mx[4];
#pragma unroll
    for (int r = 0; r < 4; r++) {
      const int qg = qw + l4 * 4 + r;
      float s0 = sv0[r] * scale;
      float s1 = sv1[r] * scale;
      if (kb + l15 > qg) s0 = -INFINITY;
      if (kb + 16 + l15 > qg) s1 = -INFINITY;
      sv0[r] = s0; sv1[r] = s1;
      float m_ = fmaxf(s0, s1);
      m_ = fmaxf(m_, __shfl_xor(m_, 1, 64));
      m_ = fmaxf(m_, __shfl_xor(m_, 2, 64));
      m_ = fmaxf(m_, __shfl_xor(m_, 4, 64));
      m_ = fmaxf(m_, __shfl_xor(m_, 8, 64));
      mx[r] = m_;
    }
    bool need = (mx[0] > mrow[0] + 8.f) || (mx[1] > mrow[1] + 8.f) ||
                (mx[2] > mrow[2] + 8.f) || (mx[3] > mrow[3] + 8.f);
    if (__any(need)) {
      float alpha[4];
#pragma unroll
      for (int r = 0; r < 4; r++) {
        float mn = fmaxf(mrow[r], mx[r]);
        alpha[r] = __expf(mrow[r] - mn);
        lrow[r] *= alpha[r];
        mrow[r] = mn;
      }
#pragma unroll
      for (int n = 0; n < 32; n++) {
#pragma unroll
        for (int r = 0; r < 4; r++) acc[n][r] *= alpha[r];
      }
    }
#pragma unroll
    for (int r = 0; r < 4; r++) {
      float p0 = __expf(sv0[r] - mrow[r]);
      float p1 = __expf(sv1[r] - mrow[r]);
      float rs = p0 + p1;
      rs += __shfl_xor(rs, 1, 64);
      rs += __shfl_xor(rs, 2, 64);
      rs += __shfl_xor(rs, 4, 64);
      rs += __shfl_xor(rs, 8, 64);
      lrow[r] += rs;
      __bf16* P = &Ps[wid][0];
      P[(l4 * 4 + r) * 40 + l15] = (__bf16)p0;
      P[(l4 * 4 + r) * 40 + 16 + l15] = (__bf16)p1;
    }

    __syncthreads();                   // barrier2: drains V(kt); all waves done with Ks
    if (kt + 1 < kt1) stageK(kt + 1);  // flies under PV

    bf16x8 pf = *reinterpret_cast<const bf16x8*>(&Ps[wid][0] + l15 * 40 + l4 * 8);
#pragma unroll
    for (int n = 0; n < 32; n++) {
      const int row = n * 16 + l15;
      bf16x8 vb = *reinterpret_cast<const bf16x8*>(Vts + row * 32 + ((l4 * 8) ^ (((row >> 1) & 3) << 3)));
      acc[n] = MFMA16(pf, vb, acc[n]);
    }
  }

  __bf16* Osel = ks ? O1 : O0;
#pragma unroll
  for (int r = 0; r < 4; r++) {
    const int qg = qw + l4 * 4 + r;
    const float inv = (lrow[r] > 0.f) ? (1.0f / lrow[r]) : 0.f;  // empty partial -> zeros
    __bf16* Og = Osel + ((size_t)(b * 2048 + qg) * (512 * G) + hl * 512);
#pragma unroll
    for (int n = 0; n < 32; n++) Og[n * 16 + l15] = (__bf16)(acc[n][r] * inv);
    if (l15 == 0) Ml[ks * bhN * 2048 + bh * 2048 + qg] = make_float2(mrow[r], lrow[r]);
  }
}

// ---------------- split-K merge weights: Wm[bh*2048+m] = (a0, a1) ----------------
__global__ void weights_k(const float2* __restrict__ Ml, float2* __restrict__ Wm,
                          int G, int nrow) {
  int idx = blockIdx.x * 256 + threadIdx.x;
  if (idx >= nrow) return;  // idx = bh*2048 + m
  const int bhN = 4 * G;
  float2 ml0 = Ml[idx];
  float2 ml1 = Ml[bhN * 2048 + idx];
  float mm = fmaxf(ml0.x, ml1.x);
  float w0 = __expf(ml0.x - mm) * ml0.y;
  bool h1 = (ml1.y > 0.f);  // false for empty partials
  float w1 = h1 ? __expf(ml1.x - mm) * ml1.y : 0.f;
  float inv = 1.f / (w0 + w1);
  Wm[idx] = make_float2(w0 * inv, h1 ? w1 * inv : 0.f);
}

// ---------------- fused output projection: merge O0/O1 during A-staging ----------------
__global__ __launch_bounds__(256) void out_gemm_f_k(
    const __bf16* __restrict__ O0, const __bf16* __restrict__ O1,
    const float2* __restrict__ Wm, const __bf16* __restrict__ Wo,
    const float* __restrict__ bias, float* __restrict__ Y, int G, int lg, int first) {
  const int AS = 512 * G;
  const int mbase = blockIdx.x * 128, nbase = blockIdx.y * 64;
  __shared__ alignas(16) __bf16 As[128 * 64];
  __shared__ alignas(16) __bf16 Bs[64 * 64];
  const int tid = threadIdx.x;
  const int lane = tid & 63, wid = tid >> 6;
  const int wr = wid >> 1, wc = wid & 1;
  const int l15 = lane & 15, l4 = lane >> 4;

  f32x4 acc[4][2];
#pragma unroll
  for (int i = 0; i < 4; i++)
#pragma unroll
    for (int j = 0; j < 2; j++) acc[i][j] = f32x4{0.f, 0.f, 0.f, 0.f};

  const int nkt = 8 * G;
  for (int kt = 0; kt < nkt; ++kt) {
    const int kb = kt * 64;
    const int hl = kb >> 9;  // head of this K-tile
    // A: reg-staged merge of O0/O1 (guarded: w.y==0 rows never use O1 values)
    bf16x8 av[4];
    int chk[4];
#pragma unroll
    for (int i = 0; i < 4; i++) {
      int chunk = i * 256 + tid;
      chk[i] = chunk;
      int row = chunk >> 3, col = (chunk & 7) * 8;
      int g = mbase + row;
      int m = g & 2047, b_ = g >> 11;
      float2 w = Wm[(b_ * G + hl) * 2048 + m];
      bf16x8 v0 = *reinterpret_cast<const bf16x8*>(O0 + (size_t)g * AS + kb + col);
      bf16x8 v1 = *reinterpret_cast<const bf16x8*>(O1 + (size_t)g * AS + kb + col);
      bf16x8 o;
      const bool use1 = (w.y > 0.f);
#pragma unroll
      for (int j = 0; j < 8; j++) {
        float t = use1 ? (w.y * (float)v1[j]) : 0.f;  // select kills NaN partials
        o[j] = (__bf16)(w.x * (float)v0[j] + t);
      }
      av[i] = o;
    }
    // B via async g2l16
#pragma unroll
    for (int i = 0; i < 2; i++) {
      int chunk = i * 256 + tid;
      int row = chunk >> 3, col = (chunk & 7) * 8;
      g2l16(Wo + (size_t)(nbase + row) * 4096 + kb + col, Bs + (i * 256 + (tid & ~63)) * 8);
    }
#pragma unroll
    for (int i = 0; i < 4; i++)
      *reinterpret_cast<bf16x8*>(As + chk[i] * 8) = av[i];
    __syncthreads();
#pragma unroll
    for (int kk = 0; kk < 2; ++kk) {
      bf16x8 a[4], b[2];
#pragma unroll
      for (int i = 0; i < 4; i++)
        a[i] = *reinterpret_cast<const bf16x8*>(As + (wr * 64 + i * 16 + l15) * 64 + kk * 32 + l4 * 8);
#pragma unroll
      for (int j = 0; j < 2; j++)
        b[j] = *reinterpret_cast<const bf16x8*>(Bs + (wc * 32 + j * 16 + l15) * 64 + kk * 32 + l4 * 8);
#pragma unroll
      for (int i = 0; i < 4; i++)
#pragma unroll
        for (int j = 0; j < 2; j++) acc[i][j] = MFMA16(a[i], b[j], acc[i][j]);
    }
    __syncthreads();
  }

#pragma unroll
  for (int i = 0; i < 4; i++) {
#pragma unroll
    for (int j = 0; j < 2; j++) {
      const int col = nbase + wc * 32 + j * 16 + l15;
#pragma unroll
      for (int r = 0; r < 4; r++) {
        const int row = mbase + wr * 64 + i * 16 + l4 * 4 + r;
        float prev = first ? bias[col] : Y[(size_t)row * 512 + col];
        Y[(size_t)row * 512 + col] = prev + acc[i][j][r];
      }
    }
  }
}

// ---------------- plain output projection (non-split fallback) ----------------
__global__ __launch_bounds__(256) void out_gemm_k(
    const __bf16* __restrict__ A, const __bf16* __restrict__ Wo,
    const float* __restrict__ bias, float* __restrict__ Y, int G, int first) {
  const int AS = 512 * G;
  const int mbase = blockIdx.x * 128, nbase = blockIdx.y * 64;
  __shared__ alignas(16) __bf16 As[128 * 64];
  __shared__ alignas(16) __bf16 Bs[64 * 64];
  const int tid = threadIdx.x;
  const int lane = tid & 63, wid = tid >> 6;
  const int wr = wid >> 1, wc = wid & 1;
  const int l15 = lane & 15, l4 = lane >> 4;

  f32x4 acc[4][2];
#pragma unroll
  for (int i = 0; i < 4; i++)
#pragma unroll
    for (int j = 0; j < 2; j++) acc[i][j] = f32x4{0.f, 0.f, 0.f, 0.f};

  const int nkt = 8 * G;
  for (int kt = 0; kt < nkt; ++kt) {
    const int kb = kt * 64;
#pragma unroll
    for (int i = 0; i < 4; i++) {
      int chunk = i * 256 + tid;
      int row = chunk >> 3, col = (chunk & 7) * 8;
      g2l16(A + (size_t)(mbase + row) * AS + kb + col, As + (i * 256 + (tid & ~63)) * 8);
    }
#pragma unroll
    for (int i = 0; i < 2; i++) {
      int chunk = i * 256 + tid;
      int row = chunk >> 3, col = (chunk & 7) * 8;
      g2l16(Wo + (size_t)(nbase + row) * 4096 + kb + col, Bs + (i * 256 + (tid & ~63)) * 8);
    }
    __syncthreads();
#pragma unroll
    for (int kk = 0; kk < 2; ++kk) {
      bf16x8 a[4], b[2];
#pragma unroll
      for (int i = 0; i < 4; i++)
        a[i] = *reinterpret_cast<const bf16x8*>(As + (wr * 64 + i * 16 + l15) * 64 + kk * 32 + l4 * 8);
#pragma unroll
      for (int j = 0; j < 2; j++)
        b[j] = *reinterpret_cast<const bf16x8*>(Bs + (wc * 32 + j * 16 + l15) * 64 + kk * 32 + l4 * 8);
#pragma unroll
      for (int i = 0; i < 4; i++)
#pragma unroll
        for (int j = 0; j < 2; j++) acc[i][j] = MFMA16(a[i], b[j], acc[i][j]);
    }
    __syncthreads();
  }

#pragma unroll
  for (int i = 0; i < 4; i++) {
#pragma unroll
    for (int j = 0; j < 2; j++) {
      const int col = nbase + wc * 32 + j * 16 + l15;
#pragma unroll
      for (int r = 0; r < 4; r++) {
        const int row = mbase + wr * 64 + i * 16 + l4 * 4 + r;
        float prev = first ? bias[col] : Y[(size_t)row * 512 + col];
        Y[(size_t)row * 512 + col] = prev + acc[i][j][r];
      }
    }
  }
}

extern "C" void kernel_launch(void* const* d_in, const int* in_sizes, int n_in,
                              void* d_out, int out_size, void* d_ws, size_t ws_size,
                              hipStream_t stream) {
  (void)in_sizes; (void)n_in; (void)out_size;
  const float* x = (const float*)d_in[0];
  const float* wq = (const float*)d_in[1];
  const float* wk = (const float*)d_in[2];
  const float* wv = (const float*)d_in[3];
  const float* wo = (const float*)d_in[4];
  const float* bo = (const float*)d_in[5];
  float* y = (float*)d_out;

  char* base = (char*)d_ws;
  size_t off = 0;
  auto alloc = [&](size_t bytes) -> void* {
    void* p = base + off;
    off += (bytes + 255) & ~(size_t)255;
    return p;
  };
  __bf16* xb = (__bf16*)alloc((size_t)8192 * 512 * 2);
  __bf16* wqb = (__bf16*)alloc((size_t)8 * 512 * 512 * 2);
  __bf16* wkb = (__bf16*)alloc((size_t)8 * 512 * 512 * 2);
  __bf16* wvb = (__bf16*)alloc((size_t)8 * 512 * 512 * 2);
  __bf16* wob = (__bf16*)alloc((size_t)512 * 4096 * 2);
  float* ct = (float*)alloc((size_t)2048 * 256 * 4);
  float* st = (float*)alloc((size_t)2048 * 256 * 4);
  const size_t persist = off;

  int G = 0, lg = 0;
  for (int g = 8, l = 3; g >= 1; g >>= 1, --l) {
    size_t T = ((size_t)g * 4 * 2048 * 512 * 2 + 255) & ~(size_t)255;
    if (persist + 4 * T <= ws_size) { G = g; lg = l; break; }
  }
  if (G == 0) return;

  const int bhN = 4 * G;
  size_t T = ((size_t)G * 4 * 2048 * 512 * 2 + 255) & ~(size_t)255;
  size_t mlBytes = ((size_t)2 * bhN * 2048 * sizeof(float2) + 255) & ~(size_t)255;
  size_t wmBytes = ((size_t)bhN * 2048 * sizeof(float2) + 255) & ~(size_t)255;
  bool SPLIT = (G >= 2) && (persist + 5 * T + mlBytes + wmBytes <= ws_size);

  __bf16* Qb = (__bf16*)(base + persist);
  __bf16* Kb = (__bf16*)(base + persist + T);
  __bf16* VTb = (__bf16*)(base + persist + 2 * T);
  __bf16* Ob = (__bf16*)(base + persist + 3 * T);
  __bf16* O1b = SPLIT ? (__bf16*)(base + persist + 4 * T) : Ob;
  float2* Mlb = SPLIT ? (float2*)(base + persist + 5 * T) : (float2*)(base + persist);
  float2* Wmb = SPLIT ? (float2*)(base + persist + 5 * T + mlBytes) : (float2*)(base + persist);

  prep_k<<<14336, 256, 0, stream>>>(x, wq, wk, wv, wo, xb, wqb, wkb, wvb, wob, ct, st);

  const int nrow = bhN * 2048;
  for (int h0 = 0; h0 < 8; h0 += G) {
    qkv_gemm_k<<<dim3(64, 4, 3 * G), 256, 0, stream>>>(xb, wqb, wkb, wvb, ct, st,
                                                       Qb, Kb, VTb, G, lg, h0);
    if (SPLIT) {
      flashB_k<<<dim3(32 * bhN), 512, 0, stream>>>(Qb, Kb, VTb, Ob, O1b, Mlb, G, lg);
      weights_k<<<(nrow + 255) / 256, 256, 0, stream>>>(Mlb, Wmb, G, nrow);
      out_gemm_f_k<<<dim3(64, 8), 256, 0, stream>>>(Ob, O1b, Wmb, wob + h0 * 512, bo, y,
                                                    G, lg, h0 == 0);
    } else {
      flash_attn_k<<<dim3(16, bhN), 512, 0, stream>>>(Qb, Kb, VTb, Ob, G, lg);
      out_gemm_k<<<dim3(64, 8), 256, 0, stream>>>(Ob, wob + h0 * 512, bo, y, G, h0 == 0);
    }
  }
}

// Round 19
// 648.762 us; speedup vs baseline: 1.1009x; 1.1009x over previous
//
#include <hip/hip_runtime.h>
#include <hip/hip_bf16.h>
#include <math.h>

// B=4, M=2048, D=512, H=8. Heads in groups of G (G=4 on this harness).

typedef __attribute__((ext_vector_type(8))) __bf16 bf16x8;
typedef __attribute__((ext_vector_type(4))) __bf16 bf16x4;
typedef __attribute__((ext_vector_type(4))) float f32x4;

#define MFMA16(a, b, c) __builtin_amdgcn_mfma_f32_16x16x32_bf16((a), (b), (c), 0, 0, 0)

__device__ __forceinline__ void g2l16(const void* g, void* l) {
  __builtin_amdgcn_global_load_lds((const __attribute__((address_space(1))) void*)g,
                                   (__attribute__((address_space(3))) void*)l, 16, 0, 0);
}

// ---------------- fused prep: all fp32->bf16 casts + RoPE tables ----------------
__global__ void prep_k(const float* __restrict__ x, const float* __restrict__ wq,
                       const float* __restrict__ wk, const float* __restrict__ wv,
                       const float* __restrict__ wo,
                       __bf16* __restrict__ xb, __bf16* __restrict__ wqb,
                       __bf16* __restrict__ wkb, __bf16* __restrict__ wvb,
                       __bf16* __restrict__ wob,
                       float* __restrict__ ct, float* __restrict__ st) {
  int i = blockIdx.x * 256 + threadIdx.x;
  if (i < 3145728) {
    const float* src;
    __bf16* dst;
    int off = i;
    if (i < 1048576) { src = x; dst = xb; }
    else if (i < 1572864) { src = wq; dst = wqb; off = i - 1048576; }
    else if (i < 2097152) { src = wk; dst = wkb; off = i - 1572864; }
    else if (i < 2621440) { src = wv; dst = wvb; off = i - 2097152; }
    else { src = wo; dst = wob; off = i - 2621440; }
    float4 f = reinterpret_cast<const float4*>(src)[off];
    bf16x4 o;
    o.x = (__bf16)f.x; o.y = (__bf16)f.y; o.z = (__bf16)f.z; o.w = (__bf16)f.w;
    reinterpret_cast<bf16x4*>(dst)[off] = o;
  } else {
    int idx = i - 3145728;  // 2048*256
    int m = idx >> 8, j = idx & 255;
    float e = (-2.0f * ((float)j - 1.0f) / 512.0f) * 13.287712379549449f;  // log2(1e4)
    float theta = exp2f(e);
    float ang = (float)m * theta;
    float s, c;
    sincosf(ang, &s, &c);
    ct[idx] = c;
    st[idx] = s;
  }
}

// ---------------- QKV projection: z = which*G + hl; V written directly transposed ----------------
__global__ __launch_bounds__(256, 2) void qkv_gemm_k(
    const __bf16* __restrict__ Xb,
    const __bf16* __restrict__ Wqb, const __bf16* __restrict__ Wkb, const __bf16* __restrict__ Wvb,
    const float* __restrict__ ct, const float* __restrict__ st,
    __bf16* __restrict__ Q, __bf16* __restrict__ K, __bf16* __restrict__ VT,
    int G, int lg, int h0) {
  const int z = blockIdx.z;
  const int which = z >> lg, hl = z & (G - 1);
  const int h = h0 + hl;
  const __bf16* W = (which == 0 ? Wqb : which == 1 ? Wkb : Wvb) + (size_t)h * 262144;

  const int mbase = blockIdx.x * 128;
  const int nbase = blockIdx.y * 128;

  __shared__ alignas(16) __bf16 As[128 * 64];
  __shared__ alignas(16) __bf16 Bs[128 * 64];

  const int tid = threadIdx.x;
  const int lane = tid & 63, wid = tid >> 6;
  const int wr = wid >> 1, wc = wid & 1;
  const int l15 = lane & 15, l4 = lane >> 4;

  f32x4 acc[4][4];
#pragma unroll
  for (int i = 0; i < 4; i++)
#pragma unroll
    for (int j = 0; j < 4; j++) acc[i][j] = f32x4{0.f, 0.f, 0.f, 0.f};

  for (int kt = 0; kt < 8; ++kt) {
    const int kb = kt * 64;
#pragma unroll
    for (int i = 0; i < 4; i++) {
      int chunk = i * 256 + tid;
      int row = chunk >> 3, col = (chunk & 7) * 8;
      g2l16(Xb + (size_t)(mbase + row) * 512 + kb + col, As + (i * 256 + (tid & ~63)) * 8);
    }
#pragma unroll
    for (int i = 0; i < 4; i++) {
      int chunk = i * 256 + tid;
      int row = chunk >> 3, col = (chunk & 7) * 8;
      g2l16(W + (size_t)(nbase + row) * 512 + kb + col, Bs + (i * 256 + (tid & ~63)) * 8);
    }
    __syncthreads();
#pragma unroll
    for (int kk = 0; kk < 2; ++kk) {
      bf16x8 a[4], b[4];
#pragma unroll
      for (int i = 0; i < 4; i++)
        a[i] = *reinterpret_cast<const bf16x8*>(As + (wr * 64 + i * 16 + l15) * 64 + kk * 32 + l4 * 8);
#pragma unroll
      for (int j = 0; j < 4; j++)
        b[j] = *reinterpret_cast<const bf16x8*>(Bs + (wc * 64 + j * 16 + l15) * 64 + kk * 32 + l4 * 8);
#pragma unroll
      for (int i = 0; i < 4; i++)
#pragma unroll
        for (int j = 0; j < 4; j++) acc[i][j] = MFMA16(a[i], b[j], acc[i][j]);
    }
    __syncthreads();
  }

  if (which == 2) {
    const int b_ = mbase >> 11;
    const int mloc = mbase & 2047;
    __bf16* Tgw = VT + (size_t)(b_ * G + hl) * 512 * 2048;
#pragma unroll
    for (int i = 0; i < 4; i++) {
#pragma unroll
      for (int j = 0; j < 4; j++) {
        const int col = nbase + wc * 64 + j * 16 + l15;
        const int m0 = mloc + wr * 64 + i * 16 + l4 * 4;
        bf16x4 pk;
        pk.x = (__bf16)acc[i][j][0];
        pk.y = (__bf16)acc[i][j][1];
        pk.z = (__bf16)acc[i][j][2];
        pk.w = (__bf16)acc[i][j][3];
        *reinterpret_cast<bf16x4*>(&Tgw[(size_t)col * 2048 + m0]) = pk;
      }
    }
  } else {
    __bf16* Out = which ? K : Q;
#pragma unroll
    for (int i = 0; i < 4; i++) {
#pragma unroll
      for (int j = 0; j < 4; j++) {
        const int col = nbase + wc * 64 + j * 16 + l15;
#pragma unroll
        for (int r = 0; r < 4; r++) {
          const int rowg = mbase + wr * 64 + i * 16 + l4 * 4 + r;
          const int b_ = rowg >> 11, m = rowg & 2047;
          float v = acc[i][j][r];
          float pv = __shfl_xor(v, 1, 64);
          float c = ct[m * 256 + (col >> 1)];
          float s = st[m * 256 + (col >> 1)];
          v = (col & 1) ? (v * c - pv * s) : (v * c + pv * s);
          Out[(size_t)((b_ * G + hl) * 2048 + m) * 512 + col] = (__bf16)v;
        }
      }
    }
  }
}

// ---------------- non-split fallback flash (R10/R14 proven) ----------------
__global__ __launch_bounds__(512) void flash_attn_k(
    const __bf16* __restrict__ Q, const __bf16* __restrict__ K, const __bf16* __restrict__ VT,
    __bf16* __restrict__ O0, int G, int lg) {
  const int bhN = 4 * G;
  const int L = blockIdx.x + 16 * blockIdx.y;
  const int half = L / (8 * bhN);
  const int r_ = L % (8 * bhN);
  const int bh = r_ % bhN;
  const int p_ = r_ / bhN;
  const int qblk = half ? (15 - p_) : p_;
  const int b = bh >> lg, hl = bh & (G - 1);
  const int tid = threadIdx.x, lane = tid & 63, wid = tid >> 6;
  const int l15 = lane & 15, l4 = lane >> 4;
  const int qw = qblk * 128 + wid * 16;

  __shared__ alignas(16) __bf16 Ks[32 * 512];
  __shared__ alignas(16) __bf16 Vts[512 * 32];
  __shared__ alignas(16) __bf16 Ps[8][16 * 32];

  const __bf16* Qg = Q + ((size_t)bh * 2048 + qw) * 512;
  const __bf16* Kg = K + (size_t)bh * 2048 * 512;
  const __bf16* Tg = VT + (size_t)bh * 512 * 2048;

  bf16x8 qf[16];
#pragma unroll
  for (int c = 0; c < 16; c++)
    qf[c] = *reinterpret_cast<const bf16x8*>(Qg + l15 * 512 + c * 32 + l4 * 8);

  f32x4 acc[32];
#pragma unroll
  for (int n = 0; n < 32; n++) acc[n] = f32x4{0.f, 0.f, 0.f, 0.f};
  float mrow[4] = {-INFINITY, -INFINITY, -INFINITY, -INFINITY};
  float lrow[4] = {0.f, 0.f, 0.f, 0.f};

  const float scale = 0.04419417382415922f;
  const int ntiles = qblk * 4 + 4;

  for (int kt = 0; kt < ntiles; ++kt) {
    const int kb = kt * 32;
#pragma unroll
    for (int i = 0; i < 4; i++) {
      int chunk = i * 512 + tid;
      int row = chunk >> 6, c16 = chunk & 63;
      g2l16(Kg + (size_t)(kb + row) * 512 + ((c16 ^ (row & 7)) << 3),
            Ks + (i * 512 + (tid & ~63)) * 8);
    }
#pragma unroll
    for (int i = 0; i < 4; i++) {
      int chunk = i * 512 + tid;
      int row = chunk >> 2, c4 = chunk & 3;
      g2l16(Tg + (size_t)row * 2048 + kb + ((c4 ^ ((row >> 1) & 3)) << 3),
            Vts + (i * 512 + (tid & ~63)) * 8);
    }
    __syncthreads();

    f32x4 sv0 = f32x4{0.f, 0.f, 0.f, 0.f}, sv1 = f32x4{0.f, 0.f, 0.f, 0.f};
#pragma unroll
    for (int c = 0; c < 16; c++) {
      const int off = c * 32 + l4 * 8;
      const int r0 = l15, r1 = 16 + l15;
      bf16x8 b0 = *reinterpret_cast<const bf16x8*>(Ks + r0 * 512 + (off ^ ((r0 & 7) << 3)));
      bf16x8 b1 = *reinterpret_cast<const bf16x8*>(Ks + r1 * 512 + (off ^ ((r1 & 7) << 3)));
      sv0 = MFMA16(qf[c], b0, sv0);
      sv1 = MFMA16(qf[c], b1, sv1);
    }

    float mx[4];
#pragma unroll
    for (int r = 0; r < 4; r++) {
      const int qg = qw + l4 * 4 + r;
      float s0 = sv0[r] * scale;
      float s1 = sv1[r] * scale;
      if (kb + l15 > qg) s0 = -INFINITY;
      if (kb + 16 + l15 > qg) s1 = -INFINITY;
      sv0[r] = s0; sv1[r] = s1;
      float m_ = fmaxf(s0, s1);
      m_ = fmaxf(m_, __shfl_xor(m_, 1, 64));
      m_ = fmaxf(m_, __shfl_xor(m_, 2, 64));
      m_ = fmaxf(m_, __shfl_xor(m_, 4, 64));
      m_ = fmaxf(m_, __shfl_xor(m_, 8, 64));
      mx[r] = m_;
    }
    bool need = (mx[0] > mrow[0] + 8.f) || (mx[1] > mrow[1] + 8.f) ||
                (mx[2] > mrow[2] + 8.f) || (mx[3] > mrow[3] + 8.f);
    if (__any(need)) {
      float alpha[4];
#pragma unroll
      for (int r = 0; r < 4; r++) {
        float mn = fmaxf(mrow[r], mx[r]);
        alpha[r] = __expf(mrow[r] - mn);
        lrow[r] *= alpha[r];
        mrow[r] = mn;
      }
#pragma unroll
      for (int n = 0; n < 32; n++) {
#pragma unroll
        for (int r = 0; r < 4; r++) acc[n][r] *= alpha[r];
      }
    }
#pragma unroll
    for (int r = 0; r < 4; r++) {
      float p0 = __expf(sv0[r] - mrow[r]);
      float p1 = __expf(sv1[r] - mrow[r]);
      float rs = p0 + p1;
      rs += __shfl_xor(rs, 1, 64);
      rs += __shfl_xor(rs, 2, 64);
      rs += __shfl_xor(rs, 4, 64);
      rs += __shfl_xor(rs, 8, 64);
      lrow[r] += rs;
      __bf16* P = &Ps[wid][0];
      P[(l4 * 4 + r) * 32 + l15] = (__bf16)p0;
      P[(l4 * 4 + r) * 32 + 16 + l15] = (__bf16)p1;
    }
    bf16x8 pf = *reinterpret_cast<const bf16x8*>(&Ps[wid][0] + l15 * 32 + l4 * 8);
#pragma unroll
    for (int n = 0; n < 32; n++) {
      const int row = n * 16 + l15;
      bf16x8 vb = *reinterpret_cast<const bf16x8*>(Vts + row * 32 + ((l4 * 8) ^ (((row >> 1) & 3) << 3)));
      acc[n] = MFMA16(pf, vb, acc[n]);
    }
    __syncthreads();
  }

#pragma unroll
  for (int r = 0; r < 4; r++) {
    const int qg = qw + l4 * 4 + r;
    const float inv = 1.0f / lrow[r];
    __bf16* Og = O0 + ((size_t)(b * 2048 + qg) * (512 * G) + hl * 512);
#pragma unroll
    for (int n = 0; n < 32; n++) Og[n * 16 + l15] = (__bf16)(acc[n][r] * inv);
  }
}

// ---------------- flashB: split-K, 2-barrier drain-covered schedule (NaN-safe) ----------------
__global__ __launch_bounds__(512) void flashB_k(
    const __bf16* __restrict__ Q, const __bf16* __restrict__ K, const __bf16* __restrict__ VT,
    __bf16* __restrict__ O0, __bf16* __restrict__ O1, float2* __restrict__ Ml,
    int G, int lg) {
  const int bhN = 4 * G;
  const int L = blockIdx.x;
  const int bh = L % bhN;
  const int s_ = L / bhN;  // 0..31
  const int ks = (s_ < 16) ? 0 : 1;
  const int qblk = ks ? (31 - s_) : s_;
  const int hn = 2 * qblk + 2;
  const int kt0 = ks * hn, kt1 = kt0 + hn;
  const int b = bh >> lg, hl = bh & (G - 1);
  const int tid = threadIdx.x, lane = tid & 63, wid = tid >> 6;
  const int l15 = lane & 15, l4 = lane >> 4;
  const int qw = qblk * 128 + wid * 16;

  __shared__ alignas(16) __bf16 Ks[32 * 512];
  __shared__ alignas(16) __bf16 Vts[512 * 32];
  __shared__ alignas(16) __bf16 Ps[8][16 * 40];  // stride 40: aligned + write-conflict-free

  const __bf16* Qg = Q + ((size_t)bh * 2048 + qw) * 512;
  const __bf16* Kg = K + (size_t)bh * 2048 * 512;
  const __bf16* Tg = VT + (size_t)bh * 512 * 2048;

  bf16x8 qf[16];
#pragma unroll
  for (int c = 0; c < 16; c++)
    qf[c] = *reinterpret_cast<const bf16x8*>(Qg + l15 * 512 + c * 32 + l4 * 8);

  f32x4 acc[32];
#pragma unroll
  for (int n = 0; n < 32; n++) acc[n] = f32x4{0.f, 0.f, 0.f, 0.f};
  float mrow[4] = {-1e30f, -1e30f, -1e30f, -1e30f};  // finite: masked rows stay NaN-free
  float lrow[4] = {0.f, 0.f, 0.f, 0.f};

  const float scale = 0.04419417382415922f;

  auto stageK = [&](int kt2) {
#pragma unroll
    for (int i = 0; i < 4; i++) {
      int chunk = i * 512 + tid;
      int row = chunk >> 6, c16 = chunk & 63;
      g2l16(Kg + (size_t)(kt2 * 32 + row) * 512 + ((c16 ^ (row & 7)) << 3),
            Ks + (i * 512 + (tid & ~63)) * 8);
    }
  };
  auto stageV = [&](int kt2) {
#pragma unroll
    for (int i = 0; i < 4; i++) {
      int chunk = i * 512 + tid;
      int row = chunk >> 2, c4 = chunk & 3;
      g2l16(Tg + (size_t)row * 2048 + kt2 * 32 + ((c4 ^ ((row >> 1) & 3)) << 3),
            Vts + (i * 512 + (tid & ~63)) * 8);
    }
  };

  stageK(kt0);

  for (int kt = kt0; kt < kt1; ++kt) {
    const int kb = kt * 32;
    __syncthreads();  // barrier1: PV(kt-1) done; drains K(kt) (covered by prev PV)
    stageV(kt);       // flies under QK + softmax

    f32x4 sv0 = f32x4{0.f, 0.f, 0.f, 0.f}, sv1 = f32x4{0.f, 0.f, 0.f, 0.f};
#pragma unroll
    for (int c = 0; c < 16; c++) {
      const int off = c * 32 + l4 * 8;
      const int r0 = l15, r1 = 16 + l15;
      bf16x8 b0 = *reinterpret_cast<const bf16x8*>(Ks + r0 * 512 + (off ^ ((r0 & 7) << 3)));
      bf16x8 b1 = *reinterpret_cast<const bf16x8*>(Ks + r1 * 512 + (off ^ ((r1 & 7) << 3)));
      sv0 = MFMA16(qf[c], b0, sv0);
      sv1 = MFMA16(qf[c], b1, sv1);
    }

    float mx[4];
#pragma unroll
    for (int r = 0; r < 4; r++) {
      const int qg = qw + l4 * 4 + r;
      float s0 = sv0[r] * scale;
      float s1 = sv1[r] * scale;
      if (kb + l15 > qg) s0 = -INFINITY;
      if (kb + 16 + l15 > qg) s1 = -INFINITY;
      sv0[r] = s0; sv1[r] = s1;
      float m_ = fmaxf(s0, s1);
      m_ = fmaxf(m_, __shfl_xor(m_, 1, 64));
      m_ = fmaxf(m_, __shfl_xor(m_, 2, 64));
      m_ = fmaxf(m_, __shfl_xor(m_, 4, 64));
      m_ = fmaxf(m_, __shfl_xor(m_, 8, 64));
      mx[r] = m_;
    }
    bool need = (mx[0] > mrow[0] + 8.f) || (mx[1] > mrow[1] + 8.f) ||
                (mx[2] > mrow[2] + 8.f) || (mx[3] > mrow[3] + 8.f);
    if (__any(need)) {
      float alpha[4];
#pragma unroll
      for (int r = 0; r < 4; r++) {
        float mn = fmaxf(mrow[r], mx[r]);
        alpha[r] = __expf(mrow[r] - mn);
        lrow[r] *= alpha[r];
        mrow[r] = mn;
      }
#pragma unroll
      for (int n = 0; n < 32; n++) {
#pragma unroll
        for (int r = 0; r < 4; r++) acc[n][r] *= alpha[r];
      }
    }
#pragma unroll
    for (int r = 0; r < 4; r++) {
      float p0 = __expf(sv0[r] - mrow[r]);
      float p1 = __expf(sv1[r] - mrow[r]);
      float rs = p0 + p1;
      rs += __shfl_xor(rs, 1, 64);
      rs += __shfl_xor(rs, 2, 64);
      rs += __shfl_xor(rs, 4, 64);
      rs += __shfl_xor(rs, 8, 64);
      lrow[r] += rs;
      __bf16* P = &Ps[wid][0];
      P[(l4 * 4 + r) * 40 + l15] = (__bf16)p0;
      P[(l4 * 4 + r) * 40 + 16 + l15] = (__bf16)p1;
    }

    __syncthreads();                   // barrier2: drains V(kt); all waves done with Ks
    if (kt + 1 < kt1) stageK(kt + 1);  // flies under PV

    bf16x8 pf = *reinterpret_cast<const bf16x8*>(&Ps[wid][0] + l15 * 40 + l4 * 8);
#pragma unroll
    for (int n = 0; n < 32; n++) {
      const int row = n * 16 + l15;
      bf16x8 vb = *reinterpret_cast<const bf16x8*>(Vts + row * 32 + ((l4 * 8) ^ (((row >> 1) & 3) << 3)));
      acc[n] = MFMA16(pf, vb, acc[n]);
    }
  }

  __bf16* Osel = ks ? O1 : O0;
#pragma unroll
  for (int r = 0; r < 4; r++) {
    const int qg = qw + l4 * 4 + r;
    const float inv = (lrow[r] > 0.f) ? (1.0f / lrow[r]) : 0.f;  // empty partial -> zeros
    __bf16* Og = Osel + ((size_t)(b * 2048 + qg) * (512 * G) + hl * 512);
#pragma unroll
    for (int n = 0; n < 32; n++) Og[n * 16 + l15] = (__bf16)(acc[n][r] * inv);
    if (l15 == 0) Ml[ks * bhN * 2048 + bh * 2048 + qg] = make_float2(mrow[r], lrow[r]);
  }
}

// ---------------- split-K merge (R16 proven): O0 = (w0*O0 + w1*O1)/(w0+w1) ----------------
__global__ void merge_k(__bf16* __restrict__ O0, const __bf16* __restrict__ O1,
                        const float2* __restrict__ Ml, int G, int lg, int n8) {
  int idx = blockIdx.x * 256 + threadIdx.x;
  if (idx >= n8) return;
  const int bhN = 4 * G;
  size_t flat = (size_t)idx * 8;
  int rowG = (int)(flat >> 9);
  int hl = rowG & (G - 1);
  int bm = rowG >> lg;
  int b = bm >> 11, m = bm & 2047;
  int bh = b * G + hl;
  float2 ml0 = Ml[bh * 2048 + m];
  float2 ml1 = Ml[bhN * 2048 + bh * 2048 + m];
  float mm = fmaxf(ml0.x, ml1.x);
  float w0 = __expf(ml0.x - mm) * ml0.y;
  bool h1 = (ml1.y > 0.f);
  float w1 = h1 ? __expf(ml1.x - mm) * ml1.y : 0.f;
  float inv = 1.f / (w0 + w1);
  float a0 = w0 * inv, a1 = w1 * inv;
  bf16x8 v0 = *reinterpret_cast<const bf16x8*>(O0 + flat);
  bf16x8 out;
  if (h1) {
    bf16x8 v1 = *reinterpret_cast<const bf16x8*>(O1 + flat);
#pragma unroll
    for (int j = 0; j < 8; j++) out[j] = (__bf16)(a0 * (float)v0[j] + a1 * (float)v1[j]);
  } else {
#pragma unroll
    for (int j = 0; j < 8; j++) out[j] = (__bf16)(a0 * (float)v0[j]);
  }
  *reinterpret_cast<bf16x8*>(O0 + flat) = out;
}

// ---------------- split-K merge weights: Wm[bh*2048+m] = (a0, a1) ----------------
__global__ void weights_k(const float2* __restrict__ Ml, float2* __restrict__ Wm,
                          int G, int nrow) {
  int idx = blockIdx.x * 256 + threadIdx.x;
  if (idx >= nrow) return;  // idx = bh*2048 + m
  const int bhN = 4 * G;
  float2 ml0 = Ml[idx];
  float2 ml1 = Ml[bhN * 2048 + idx];
  float mm = fmaxf(ml0.x, ml1.x);
  float w0 = __expf(ml0.x - mm) * ml0.y;
  bool h1 = (ml1.y > 0.f);
  float w1 = h1 ? __expf(ml1.x - mm) * ml1.y : 0.f;
  float inv = 1.f / (w0 + w1);
  Wm[idx] = make_float2(w0 * inv, h1 ? w1 * inv : 0.f);
}

// ---------------- out_gemm_f2: fused merge with PREFETCHED A-staging (A/B experiment) ----------------
// loadA(kt+1) issued after the mid barrier -> flies under MFMA compute, drained at the
// next top barrier one compute-phase later (flashB pattern). ds_write layout == g2l16 layout.
__global__ __launch_bounds__(256) void out_gemm_f2_k(
    const __bf16* __restrict__ O0, const __bf16* __restrict__ O1,
    const float2* __restrict__ Wm, const __bf16* __restrict__ Wo,
    const float* __restrict__ bias, float* __restrict__ Y, int G, int lg, int first) {
  const int AS = 512 * G;
  const int mbase = blockIdx.x * 128, nbase = blockIdx.y * 64;
  __shared__ alignas(16) __bf16 As[128 * 64];
  __shared__ alignas(16) __bf16 Bs[64 * 64];
  const int tid = threadIdx.x;
  const int lane = tid & 63, wid = tid >> 6;
  const int wr = wid >> 1, wc = wid & 1;
  const int l15 = lane & 15, l4 = lane >> 4;

  f32x4 acc[4][2];
#pragma unroll
  for (int i = 0; i < 4; i++)
#pragma unroll
    for (int j = 0; j < 2; j++) acc[i][j] = f32x4{0.f, 0.f, 0.f, 0.f};

  bf16x8 v0r[4], v1r[4];
  float2 wreg[4];
  auto loadA = [&](int kt2) {
    const int kb2 = kt2 * 64;
    const int hl2 = kb2 >> 9;
#pragma unroll
    for (int i = 0; i < 4; i++) {
      int chunk = i * 256 + tid;
      int row = chunk >> 3, col = (chunk & 7) * 8;
      int g = mbase + row;
      int m = g & 2047, b_ = g >> 11;
      wreg[i] = Wm[(b_ * G + hl2) * 2048 + m];
      v0r[i] = *reinterpret_cast<const bf16x8*>(O0 + (size_t)g * AS + kb2 + col);
      v1r[i] = *reinterpret_cast<const bf16x8*>(O1 + (size_t)g * AS + kb2 + col);
    }
  };

  const int nkt = 8 * G;
  loadA(0);
  for (int kt = 0; kt < nkt; ++kt) {
    const int kb = kt * 64;
    // merge + commit A(kt) (regs loaded one phase ago; waits resolved naturally)
#pragma unroll
    for (int i = 0; i < 4; i++) {
      int chunk = i * 256 + tid;
      float2 w = wreg[i];
      const bool use1 = (w.y > 0.f);
      bf16x8 o;
#pragma unroll
      for (int j = 0; j < 8; j++) {
        float t = use1 ? (w.y * (float)v1r[i][j]) : 0.f;
        o[j] = (__bf16)(w.x * (float)v0r[i][j] + t);
      }
      *reinterpret_cast<bf16x8*>(As + chunk * 8) = o;
    }
    // B via async g2l16
#pragma unroll
    for (int i = 0; i < 2; i++) {
      int chunk = i * 256 + tid;
      int row = chunk >> 3, col = (chunk & 7) * 8;
      g2l16(Wo + (size_t)(nbase + row) * 4096 + kb + col, Bs + (i * 256 + (tid & ~63)) * 8);
    }
    __syncthreads();  // mid: B landed, As writes visible
    if (kt + 1 < nkt) loadA(kt + 1);  // flies under MFMA, drained next top barrier
#pragma unroll
    for (int kk = 0; kk < 2; ++kk) {
      bf16x8 a[4], b[2];
#pragma unroll
      for (int i = 0; i < 4; i++)
        a[i] = *reinterpret_cast<const bf16x8*>(As + (wr * 64 + i * 16 + l15) * 64 + kk * 32 + l4 * 8);
#pragma unroll
      for (int j = 0; j < 2; j++)
        b[j] = *reinterpret_cast<const bf16x8*>(Bs + (wc * 32 + j * 16 + l15) * 64 + kk * 32 + l4 * 8);
#pragma unroll
      for (int i = 0; i < 4; i++)
#pragma unroll
        for (int j = 0; j < 2; j++) acc[i][j] = MFMA16(a[i], b[j], acc[i][j]);
    }
    __syncthreads();  // top-equivalent: As/Bs free for next iter
  }

#pragma unroll
  for (int i = 0; i < 4; i++) {
#pragma unroll
    for (int j = 0; j < 2; j++) {
      const int col = nbase + wc * 32 + j * 16 + l15;
#pragma unroll
      for (int r = 0; r < 4; r++) {
        const int row = mbase + wr * 64 + i * 16 + l4 * 4 + r;
        float prev = first ? bias[col] : Y[(size_t)row * 512 + col];
        Y[(size_t)row * 512 + col] = prev + acc[i][j][r];
      }
    }
  }
}

// ---------------- plain output projection ----------------
__global__ __launch_bounds__(256) void out_gemm_k(
    const __bf16* __restrict__ A, const __bf16* __restrict__ Wo,
    const float* __restrict__ bias, float* __restrict__ Y, int G, int first) {
  const int AS = 512 * G;
  const int mbase = blockIdx.x * 128, nbase = blockIdx.y * 64;
  __shared__ alignas(16) __bf16 As[128 * 64];
  __shared__ alignas(16) __bf16 Bs[64 * 64];
  const int tid = threadIdx.x;
  const int lane = tid & 63, wid = tid >> 6;
  const int wr = wid >> 1, wc = wid & 1;
  const int l15 = lane & 15, l4 = lane >> 4;

  f32x4 acc[4][2];
#pragma unroll
  for (int i = 0; i < 4; i++)
#pragma unroll
    for (int j = 0; j < 2; j++) acc[i][j] = f32x4{0.f, 0.f, 0.f, 0.f};

  const int nkt = 8 * G;
  for (int kt = 0; kt < nkt; ++kt) {
    const int kb = kt * 64;
#pragma unroll
    for (int i = 0; i < 4; i++) {
      int chunk = i * 256 + tid;
      int row = chunk >> 3, col = (chunk & 7) * 8;
      g2l16(A + (size_t)(mbase + row) * AS + kb + col, As + (i * 256 + (tid & ~63)) * 8);
    }
#pragma unroll
    for (int i = 0; i < 2; i++) {
      int chunk = i * 256 + tid;
      int row = chunk >> 3, col = (chunk & 7) * 8;
      g2l16(Wo + (size_t)(nbase + row) * 4096 + kb + col, Bs + (i * 256 + (tid & ~63)) * 8);
    }
    __syncthreads();
#pragma unroll
    for (int kk = 0; kk < 2; ++kk) {
      bf16x8 a[4], b[2];
#pragma unroll
      for (int i = 0; i < 4; i++)
        a[i] = *reinterpret_cast<const bf16x8*>(As + (wr * 64 + i * 16 + l15) * 64 + kk * 32 + l4 * 8);
#pragma unroll
      for (int j = 0; j < 2; j++)
        b[j] = *reinterpret_cast<const bf16x8*>(Bs + (wc * 32 + j * 16 + l15) * 64 + kk * 32 + l4 * 8);
#pragma unroll
      for (int i = 0; i < 4; i++)
#pragma unroll
        for (int j = 0; j < 2; j++) acc[i][j] = MFMA16(a[i], b[j], acc[i][j]);
    }
    __syncthreads();
  }

#pragma unroll
  for (int i = 0; i < 4; i++) {
#pragma unroll
    for (int j = 0; j < 2; j++) {
      const int col = nbase + wc * 32 + j * 16 + l15;
#pragma unroll
      for (int r = 0; r < 4; r++) {
        const int row = mbase + wr * 64 + i * 16 + l4 * 4 + r;
        float prev = first ? bias[col] : Y[(size_t)row * 512 + col];
        Y[(size_t)row * 512 + col] = prev + acc[i][j][r];
      }
    }
  }
}

extern "C" void kernel_launch(void* const* d_in, const int* in_sizes, int n_in,
                              void* d_out, int out_size, void* d_ws, size_t ws_size,
                              hipStream_t stream) {
  (void)in_sizes; (void)n_in; (void)out_size;
  const float* x = (const float*)d_in[0];
  const float* wq = (const float*)d_in[1];
  const float* wk = (const float*)d_in[2];
  const float* wv = (const float*)d_in[3];
  const float* wo = (const float*)d_in[4];
  const float* bo = (const float*)d_in[5];
  float* y = (float*)d_out;

  char* base = (char*)d_ws;
  size_t off = 0;
  auto alloc = [&](size_t bytes) -> void* {
    void* p = base + off;
    off += (bytes + 255) & ~(size_t)255;
    return p;
  };
  __bf16* xb = (__bf16*)alloc((size_t)8192 * 512 * 2);
  __bf16* wqb = (__bf16*)alloc((size_t)8 * 512 * 512 * 2);
  __bf16* wkb = (__bf16*)alloc((size_t)8 * 512 * 512 * 2);
  __bf16* wvb = (__bf16*)alloc((size_t)8 * 512 * 512 * 2);
  __bf16* wob = (__bf16*)alloc((size_t)512 * 4096 * 2);
  float* ct = (float*)alloc((size_t)2048 * 256 * 4);
  float* st = (float*)alloc((size_t)2048 * 256 * 4);
  const size_t persist = off;

  int G = 0, lg = 0;
  for (int g = 8, l = 3; g >= 1; g >>= 1, --l) {
    size_t T = ((size_t)g * 4 * 2048 * 512 * 2 + 255) & ~(size_t)255;
    if (persist + 4 * T <= ws_size) { G = g; lg = l; break; }
  }
  if (G == 0) return;

  const int bhN = 4 * G;
  size_t T = ((size_t)G * 4 * 2048 * 512 * 2 + 255) & ~(size_t)255;
  size_t mlBytes = ((size_t)2 * bhN * 2048 * sizeof(float2) + 255) & ~(size_t)255;
  size_t wmBytes = ((size_t)bhN * 2048 * sizeof(float2) + 255) & ~(size_t)255;
  bool SPLIT = (G >= 2) && (persist + 5 * T + mlBytes + wmBytes <= ws_size);

  __bf16* Qb = (__bf16*)(base + persist);
  __bf16* Kb = (__bf16*)(base + persist + T);
  __bf16* VTb = (__bf16*)(base + persist + 2 * T);
  __bf16* Ob = (__bf16*)(base + persist + 3 * T);
  __bf16* O1b = SPLIT ? (__bf16*)(base + persist + 4 * T) : Ob;
  float2* Mlb = SPLIT ? (float2*)(base + persist + 5 * T) : (float2*)(base + persist);
  float2* Wmb = SPLIT ? (float2*)(base + persist + 5 * T + mlBytes) : (float2*)(base + persist);

  prep_k<<<14336, 256, 0, stream>>>(x, wq, wk, wv, wo, xb, wqb, wkb, wvb, wob, ct, st);

  const int nrow = bhN * 2048;
  const int n8 = bhN * 2048 * 64;
  for (int h0 = 0; h0 < 8; h0 += G) {
    qkv_gemm_k<<<dim3(64, 4, 3 * G), 256, 0, stream>>>(xb, wqb, wkb, wvb, ct, st,
                                                       Qb, Kb, VTb, G, lg, h0);
    if (SPLIT) {
      flashB_k<<<dim3(32 * bhN), 512, 0, stream>>>(Qb, Kb, VTb, Ob, O1b, Mlb, G, lg);
      if (h0 == 0) {
        // A: R16 proven path
        merge_k<<<(n8 + 255) / 256, 256, 0, stream>>>(Ob, O1b, Mlb, G, lg, n8);
        out_gemm_k<<<dim3(64, 8), 256, 0, stream>>>(Ob, wob + h0 * 512, bo, y, G, h0 == 0);
      } else {
        // B: prefetched fused merge
        weights_k<<<(nrow + 255) / 256, 256, 0, stream>>>(Mlb, Wmb, G, nrow);
        out_gemm_f2_k<<<dim3(64, 8), 256, 0, stream>>>(Ob, O1b, Wmb, wob + h0 * 512, bo, y,
                                                       G, lg, h0 == 0);
      }
    } else {
      flash_attn_k<<<dim3(16, bhN), 512, 0, stream>>>(Qb, Kb, VTb, Ob, G, lg);
      out_gemm_k<<<dim3(64, 8), 256, 0, stream>>>(Ob, wob + h0 * 512, bo, y, G, h0 == 0);
    }
  }
}

// Round 20
// 628.732 us; speedup vs baseline: 1.1360x; 1.0319x over previous
//
#include <hip/hip_runtime.h>
#include <hip/hip_bf16.h>
#include <math.h>

// B=4, M=2048, D=512, H=8. Heads in groups of G (G=4 on this harness).
// R20 = exact revert to the round-16 best configuration (630 us).

typedef __attribute__((ext_vector_type(8))) __bf16 bf16x8;
typedef __attribute__((ext_vector_type(4))) __bf16 bf16x4;
typedef __attribute__((ext_vector_type(4))) float f32x4;

#define MFMA16(a, b, c) __builtin_amdgcn_mfma_f32_16x16x32_bf16((a), (b), (c), 0, 0, 0)

__device__ __forceinline__ void g2l16(const void* g, void* l) {
  __builtin_amdgcn_global_load_lds((const __attribute__((address_space(1))) void*)g,
                                   (__attribute__((address_space(3))) void*)l, 16, 0, 0);
}

// ---------------- fused prep: all fp32->bf16 casts + RoPE tables ----------------
__global__ void prep_k(const float* __restrict__ x, const float* __restrict__ wq,
                       const float* __restrict__ wk, const float* __restrict__ wv,
                       const float* __restrict__ wo,
                       __bf16* __restrict__ xb, __bf16* __restrict__ wqb,
                       __bf16* __restrict__ wkb, __bf16* __restrict__ wvb,
                       __bf16* __restrict__ wob,
                       float* __restrict__ ct, float* __restrict__ st) {
  int i = blockIdx.x * 256 + threadIdx.x;
  if (i < 3145728) {
    const float* src;
    __bf16* dst;
    int off = i;
    if (i < 1048576) { src = x; dst = xb; }
    else if (i < 1572864) { src = wq; dst = wqb; off = i - 1048576; }
    else if (i < 2097152) { src = wk; dst = wkb; off = i - 1572864; }
    else if (i < 2621440) { src = wv; dst = wvb; off = i - 2097152; }
    else { src = wo; dst = wob; off = i - 2621440; }
    float4 f = reinterpret_cast<const float4*>(src)[off];
    bf16x4 o;
    o.x = (__bf16)f.x; o.y = (__bf16)f.y; o.z = (__bf16)f.z; o.w = (__bf16)f.w;
    reinterpret_cast<bf16x4*>(dst)[off] = o;
  } else {
    int idx = i - 3145728;  // 2048*256
    int m = idx >> 8, j = idx & 255;
    float e = (-2.0f * ((float)j - 1.0f) / 512.0f) * 13.287712379549449f;  // log2(1e4)
    float theta = exp2f(e);
    float ang = (float)m * theta;
    float s, c;
    sincosf(ang, &s, &c);
    ct[idx] = c;
    st[idx] = s;
  }
}

// ---------------- QKV projection: z = which*G + hl; V written directly transposed ----------------
__global__ __launch_bounds__(256, 2) void qkv_gemm_k(
    const __bf16* __restrict__ Xb,
    const __bf16* __restrict__ Wqb, const __bf16* __restrict__ Wkb, const __bf16* __restrict__ Wvb,
    const float* __restrict__ ct, const float* __restrict__ st,
    __bf16* __restrict__ Q, __bf16* __restrict__ K, __bf16* __restrict__ VT,
    int G, int lg, int h0) {
  const int z = blockIdx.z;
  const int which = z >> lg, hl = z & (G - 1);
  const int h = h0 + hl;
  const __bf16* W = (which == 0 ? Wqb : which == 1 ? Wkb : Wvb) + (size_t)h * 262144;

  const int mbase = blockIdx.x * 128;
  const int nbase = blockIdx.y * 128;

  __shared__ alignas(16) __bf16 As[128 * 64];
  __shared__ alignas(16) __bf16 Bs[128 * 64];

  const int tid = threadIdx.x;
  const int lane = tid & 63, wid = tid >> 6;
  const int wr = wid >> 1, wc = wid & 1;
  const int l15 = lane & 15, l4 = lane >> 4;

  f32x4 acc[4][4];
#pragma unroll
  for (int i = 0; i < 4; i++)
#pragma unroll
    for (int j = 0; j < 4; j++) acc[i][j] = f32x4{0.f, 0.f, 0.f, 0.f};

  for (int kt = 0; kt < 8; ++kt) {
    const int kb = kt * 64;
#pragma unroll
    for (int i = 0; i < 4; i++) {
      int chunk = i * 256 + tid;
      int row = chunk >> 3, col = (chunk & 7) * 8;
      g2l16(Xb + (size_t)(mbase + row) * 512 + kb + col, As + (i * 256 + (tid & ~63)) * 8);
    }
#pragma unroll
    for (int i = 0; i < 4; i++) {
      int chunk = i * 256 + tid;
      int row = chunk >> 3, col = (chunk & 7) * 8;
      g2l16(W + (size_t)(nbase + row) * 512 + kb + col, Bs + (i * 256 + (tid & ~63)) * 8);
    }
    __syncthreads();
#pragma unroll
    for (int kk = 0; kk < 2; ++kk) {
      bf16x8 a[4], b[4];
#pragma unroll
      for (int i = 0; i < 4; i++)
        a[i] = *reinterpret_cast<const bf16x8*>(As + (wr * 64 + i * 16 + l15) * 64 + kk * 32 + l4 * 8);
#pragma unroll
      for (int j = 0; j < 4; j++)
        b[j] = *reinterpret_cast<const bf16x8*>(Bs + (wc * 64 + j * 16 + l15) * 64 + kk * 32 + l4 * 8);
#pragma unroll
      for (int i = 0; i < 4; i++)
#pragma unroll
        for (int j = 0; j < 4; j++) acc[i][j] = MFMA16(a[i], b[j], acc[i][j]);
    }
    __syncthreads();
  }

  if (which == 2) {
    const int b_ = mbase >> 11;
    const int mloc = mbase & 2047;
    __bf16* Tgw = VT + (size_t)(b_ * G + hl) * 512 * 2048;
#pragma unroll
    for (int i = 0; i < 4; i++) {
#pragma unroll
      for (int j = 0; j < 4; j++) {
        const int col = nbase + wc * 64 + j * 16 + l15;
        const int m0 = mloc + wr * 64 + i * 16 + l4 * 4;
        bf16x4 pk;
        pk.x = (__bf16)acc[i][j][0];
        pk.y = (__bf16)acc[i][j][1];
        pk.z = (__bf16)acc[i][j][2];
        pk.w = (__bf16)acc[i][j][3];
        *reinterpret_cast<bf16x4*>(&Tgw[(size_t)col * 2048 + m0]) = pk;
      }
    }
  } else {
    __bf16* Out = which ? K : Q;
#pragma unroll
    for (int i = 0; i < 4; i++) {
#pragma unroll
      for (int j = 0; j < 4; j++) {
        const int col = nbase + wc * 64 + j * 16 + l15;
#pragma unroll
        for (int r = 0; r < 4; r++) {
          const int rowg = mbase + wr * 64 + i * 16 + l4 * 4 + r;
          const int b_ = rowg >> 11, m = rowg & 2047;
          float v = acc[i][j][r];
          float pv = __shfl_xor(v, 1, 64);
          float c = ct[m * 256 + (col >> 1)];
          float s = st[m * 256 + (col >> 1)];
          v = (col & 1) ? (v * c - pv * s) : (v * c + pv * s);
          Out[(size_t)((b_ * G + hl) * 2048 + m) * 512 + col] = (__bf16)v;
        }
      }
    }
  }
}

// ---------------- non-split fallback flash (R10/R14 proven) ----------------
__global__ __launch_bounds__(512) void flash_attn_k(
    const __bf16* __restrict__ Q, const __bf16* __restrict__ K, const __bf16* __restrict__ VT,
    __bf16* __restrict__ O0, int G, int lg) {
  const int bhN = 4 * G;
  const int L = blockIdx.x + 16 * blockIdx.y;
  const int half = L / (8 * bhN);
  const int r_ = L % (8 * bhN);
  const int bh = r_ % bhN;
  const int p_ = r_ / bhN;
  const int qblk = half ? (15 - p_) : p_;
  const int b = bh >> lg, hl = bh & (G - 1);
  const int tid = threadIdx.x, lane = tid & 63, wid = tid >> 6;
  const int l15 = lane & 15, l4 = lane >> 4;
  const int qw = qblk * 128 + wid * 16;

  __shared__ alignas(16) __bf16 Ks[32 * 512];
  __shared__ alignas(16) __bf16 Vts[512 * 32];
  __shared__ alignas(16) __bf16 Ps[8][16 * 32];

  const __bf16* Qg = Q + ((size_t)bh * 2048 + qw) * 512;
  const __bf16* Kg = K + (size_t)bh * 2048 * 512;
  const __bf16* Tg = VT + (size_t)bh * 512 * 2048;

  bf16x8 qf[16];
#pragma unroll
  for (int c = 0; c < 16; c++)
    qf[c] = *reinterpret_cast<const bf16x8*>(Qg + l15 * 512 + c * 32 + l4 * 8);

  f32x4 acc[32];
#pragma unroll
  for (int n = 0; n < 32; n++) acc[n] = f32x4{0.f, 0.f, 0.f, 0.f};
  float mrow[4] = {-INFINITY, -INFINITY, -INFINITY, -INFINITY};
  float lrow[4] = {0.f, 0.f, 0.f, 0.f};

  const float scale = 0.04419417382415922f;
  const int ntiles = qblk * 4 + 4;

  for (int kt = 0; kt < ntiles; ++kt) {
    const int kb = kt * 32;
#pragma unroll
    for (int i = 0; i < 4; i++) {
      int chunk = i * 512 + tid;
      int row = chunk >> 6, c16 = chunk & 63;
      g2l16(Kg + (size_t)(kb + row) * 512 + ((c16 ^ (row & 7)) << 3),
            Ks + (i * 512 + (tid & ~63)) * 8);
    }
#pragma unroll
    for (int i = 0; i < 4; i++) {
      int chunk = i * 512 + tid;
      int row = chunk >> 2, c4 = chunk & 3;
      g2l16(Tg + (size_t)row * 2048 + kb + ((c4 ^ ((row >> 1) & 3)) << 3),
            Vts + (i * 512 + (tid & ~63)) * 8);
    }
    __syncthreads();

    f32x4 sv0 = f32x4{0.f, 0.f, 0.f, 0.f}, sv1 = f32x4{0.f, 0.f, 0.f, 0.f};
#pragma unroll
    for (int c = 0; c < 16; c++) {
      const int off = c * 32 + l4 * 8;
      const int r0 = l15, r1 = 16 + l15;
      bf16x8 b0 = *reinterpret_cast<const bf16x8*>(Ks + r0 * 512 + (off ^ ((r0 & 7) << 3)));
      bf16x8 b1 = *reinterpret_cast<const bf16x8*>(Ks + r1 * 512 + (off ^ ((r1 & 7) << 3)));
      sv0 = MFMA16(qf[c], b0, sv0);
      sv1 = MFMA16(qf[c], b1, sv1);
    }

    float mx[4];
#pragma unroll
    for (int r = 0; r < 4; r++) {
      const int qg = qw + l4 * 4 + r;
      float s0 = sv0[r] * scale;
      float s1 = sv1[r] * scale;
      if (kb + l15 > qg) s0 = -INFINITY;
      if (kb + 16 + l15 > qg) s1 = -INFINITY;
      sv0[r] = s0; sv1[r] = s1;
      float m_ = fmaxf(s0, s1);
      m_ = fmaxf(m_, __shfl_xor(m_, 1, 64));
      m_ = fmaxf(m_, __shfl_xor(m_, 2, 64));
      m_ = fmaxf(m_, __shfl_xor(m_, 4, 64));
      m_ = fmaxf(m_, __shfl_xor(m_, 8, 64));
      mx[r] = m_;
    }
    bool need = (mx[0] > mrow[0] + 8.f) || (mx[1] > mrow[1] + 8.f) ||
                (mx[2] > mrow[2] + 8.f) || (mx[3] > mrow[3] + 8.f);
    if (__any(need)) {
      float alpha[4];
#pragma unroll
      for (int r = 0; r < 4; r++) {
        float mn = fmaxf(mrow[r], mx[r]);
        alpha[r] = __expf(mrow[r] - mn);
        lrow[r] *= alpha[r];
        mrow[r] = mn;
      }
#pragma unroll
      for (int n = 0; n < 32; n++) {
#pragma unroll
        for (int r = 0; r < 4; r++) acc[n][r] *= alpha[r];
      }
    }
#pragma unroll
    for (int r = 0; r < 4; r++) {
      float p0 = __expf(sv0[r] - mrow[r]);
      float p1 = __expf(sv1[r] - mrow[r]);
      float rs = p0 + p1;
      rs += __shfl_xor(rs, 1, 64);
      rs += __shfl_xor(rs, 2, 64);
      rs += __shfl_xor(rs, 4, 64);
      rs += __shfl_xor(rs, 8, 64);
      lrow[r] += rs;
      __bf16* P = &Ps[wid][0];
      P[(l4 * 4 + r) * 32 + l15] = (__bf16)p0;
      P[(l4 * 4 + r) * 32 + 16 + l15] = (__bf16)p1;
    }
    bf16x8 pf = *reinterpret_cast<const bf16x8*>(&Ps[wid][0] + l15 * 32 + l4 * 8);
#pragma unroll
    for (int n = 0; n < 32; n++) {
      const int row = n * 16 + l15;
      bf16x8 vb = *reinterpret_cast<const bf16x8*>(Vts + row * 32 + ((l4 * 8) ^ (((row >> 1) & 3) << 3)));
      acc[n] = MFMA16(pf, vb, acc[n]);
    }
    __syncthreads();
  }

#pragma unroll
  for (int r = 0; r < 4; r++) {
    const int qg = qw + l4 * 4 + r;
    const float inv = 1.0f / lrow[r];
    __bf16* Og = O0 + ((size_t)(b * 2048 + qg) * (512 * G) + hl * 512);
#pragma unroll
    for (int n = 0; n < 32; n++) Og[n * 16 + l15] = (__bf16)(acc[n][r] * inv);
  }
}

// ---------------- flashB: split-K, 2-barrier drain-covered schedule, padded Ps ----------------
// barrier1 drains K(kt) (covered by prev PV); V(kt) issued under QK+softmax; barrier2
// drains V(kt); K(kt+1) issued under PV. Ps stride 40 (80B rows): aligned b128 reads,
// conflict-free writes.
__global__ __launch_bounds__(512) void flashB_k(
    const __bf16* __restrict__ Q, const __bf16* __restrict__ K, const __bf16* __restrict__ VT,
    __bf16* __restrict__ O0, __bf16* __restrict__ O1, float2* __restrict__ Ml,
    int G, int lg) {
  const int bhN = 4 * G;
  const int L = blockIdx.x;
  const int bh = L % bhN;
  const int s_ = L / bhN;  // 0..31
  const int ks = (s_ < 16) ? 0 : 1;
  const int qblk = ks ? (31 - s_) : s_;
  const int hn = 2 * qblk + 2;
  const int kt0 = ks * hn, kt1 = kt0 + hn;
  const int b = bh >> lg, hl = bh & (G - 1);
  const int tid = threadIdx.x, lane = tid & 63, wid = tid >> 6;
  const int l15 = lane & 15, l4 = lane >> 4;
  const int qw = qblk * 128 + wid * 16;

  __shared__ alignas(16) __bf16 Ks[32 * 512];
  __shared__ alignas(16) __bf16 Vts[512 * 32];
  __shared__ alignas(16) __bf16 Ps[8][16 * 40];  // stride 40: aligned + write-conflict-free

  const __bf16* Qg = Q + ((size_t)bh * 2048 + qw) * 512;
  const __bf16* Kg = K + (size_t)bh * 2048 * 512;
  const __bf16* Tg = VT + (size_t)bh * 512 * 2048;

  bf16x8 qf[16];
#pragma unroll
  for (int c = 0; c < 16; c++)
    qf[c] = *reinterpret_cast<const bf16x8*>(Qg + l15 * 512 + c * 32 + l4 * 8);

  f32x4 acc[32];
#pragma unroll
  for (int n = 0; n < 32; n++) acc[n] = f32x4{0.f, 0.f, 0.f, 0.f};
  float mrow[4] = {-INFINITY, -INFINITY, -INFINITY, -INFINITY};
  float lrow[4] = {0.f, 0.f, 0.f, 0.f};

  const float scale = 0.04419417382415922f;

  auto stageK = [&](int kt2) {
#pragma unroll
    for (int i = 0; i < 4; i++) {
      int chunk = i * 512 + tid;
      int row = chunk >> 6, c16 = chunk & 63;
      g2l16(Kg + (size_t)(kt2 * 32 + row) * 512 + ((c16 ^ (row & 7)) << 3),
            Ks + (i * 512 + (tid & ~63)) * 8);
    }
  };
  auto stageV = [&](int kt2) {
#pragma unroll
    for (int i = 0; i < 4; i++) {
      int chunk = i * 512 + tid;
      int row = chunk >> 2, c4 = chunk & 3;
      g2l16(Tg + (size_t)row * 2048 + kt2 * 32 + ((c4 ^ ((row >> 1) & 3)) << 3),
            Vts + (i * 512 + (tid & ~63)) * 8);
    }
  };

  stageK(kt0);

  for (int kt = kt0; kt < kt1; ++kt) {
    const int kb = kt * 32;
    __syncthreads();  // barrier1: PV(kt-1) done; drains K(kt) (covered by prev PV)
    stageV(kt);       // flies under QK + softmax

    f32x4 sv0 = f32x4{0.f, 0.f, 0.f, 0.f}, sv1 = f32x4{0.f, 0.f, 0.f, 0.f};
#pragma unroll
    for (int c = 0; c < 16; c++) {
      const int off = c * 32 + l4 * 8;
      const int r0 = l15, r1 = 16 + l15;
      bf16x8 b0 = *reinterpret_cast<const bf16x8*>(Ks + r0 * 512 + (off ^ ((r0 & 7) << 3)));
      bf16x8 b1 = *reinterpret_cast<const bf16x8*>(Ks + r1 * 512 + (off ^ ((r1 & 7) << 3)));
      sv0 = MFMA16(qf[c], b0, sv0);
      sv1 = MFMA16(qf[c], b1, sv1);
    }

    float mx[4];
#pragma unroll
    for (int r = 0; r < 4; r++) {
      const int qg = qw + l4 * 4 + r;
      float s0 = sv0[r] * scale;
      float s1 = sv1[r] * scale;
      if (kb + l15 > qg) s0 = -INFINITY;
      if (kb + 16 + l15 > qg) s1 = -INFINITY;
      sv0[r] = s0; sv1[r] = s1;
      float m_ = fmaxf(s0, s1);
      m_ = fmaxf(m_, __shfl_xor(m_, 1, 64));
      m_ = fmaxf(m_, __shfl_xor(m_, 2, 64));
      m_ = fmaxf(m_, __shfl_xor(m_, 4, 64));
      m_ = fmaxf(m_, __shfl_xor(m_, 8, 64));
      mx[r] = m_;
    }
    bool need = (mx[0] > mrow[0] + 8.f) || (mx[1] > mrow[1] + 8.f) ||
                (mx[2] > mrow[2] + 8.f) || (mx[3] > mrow[3] + 8.f);
    if (__any(need)) {
      float alpha[4];
#pragma unroll
      for (int r = 0; r < 4; r++) {
        float mn = fmaxf(mrow[r], mx[r]);
        alpha[r] = __expf(mrow[r] - mn);
        lrow[r] *= alpha[r];
        mrow[r] = mn;
      }
#pragma unroll
      for (int n = 0; n < 32; n++) {
#pragma unroll
        for (int r = 0; r < 4; r++) acc[n][r] *= alpha[r];
      }
    }
#pragma unroll
    for (int r = 0; r < 4; r++) {
      float p0 = __expf(sv0[r] - mrow[r]);
      float p1 = __expf(sv1[r] - mrow[r]);
      float rs = p0 + p1;
      rs += __shfl_xor(rs, 1, 64);
      rs += __shfl_xor(rs, 2, 64);
      rs += __shfl_xor(rs, 4, 64);
      rs += __shfl_xor(rs, 8, 64);
      lrow[r] += rs;
      __bf16* P = &Ps[wid][0];
      P[(l4 * 4 + r) * 40 + l15] = (__bf16)p0;
      P[(l4 * 4 + r) * 40 + 16 + l15] = (__bf16)p1;
    }

    __syncthreads();                   // barrier2: drains V(kt); all waves done with Ks
    if (kt + 1 < kt1) stageK(kt + 1);  // flies under PV

    bf16x8 pf = *reinterpret_cast<const bf16x8*>(&Ps[wid][0] + l15 * 40 + l4 * 8);
#pragma unroll
    for (int n = 0; n < 32; n++) {
      const int row = n * 16 + l15;
      bf16x8 vb = *reinterpret_cast<const bf16x8*>(Vts + row * 32 + ((l4 * 8) ^ (((row >> 1) & 3) << 3)));
      acc[n] = MFMA16(pf, vb, acc[n]);
    }
  }

  __bf16* Osel = ks ? O1 : O0;
#pragma unroll
  for (int r = 0; r < 4; r++) {
    const int qg = qw + l4 * 4 + r;
    const float inv = 1.0f / lrow[r];
    __bf16* Og = Osel + ((size_t)(b * 2048 + qg) * (512 * G) + hl * 512);
#pragma unroll
    for (int n = 0; n < 32; n++) Og[n * 16 + l15] = (__bf16)(acc[n][r] * inv);
    if (l15 == 0) Ml[ks * bhN * 2048 + bh * 2048 + qg] = make_float2(mrow[r], lrow[r]);
  }
}

// ---------------- split-K merge ----------------
__global__ void merge_k(__bf16* __restrict__ O0, const __bf16* __restrict__ O1,
                        const float2* __restrict__ Ml, int G, int lg, int n8) {
  int idx = blockIdx.x * 256 + threadIdx.x;
  if (idx >= n8) return;
  const int bhN = 4 * G;
  size_t flat = (size_t)idx * 8;
  int rowG = (int)(flat >> 9);
  int hl = rowG & (G - 1);
  int bm = rowG >> lg;
  int b = bm >> 11, m = bm & 2047;
  int bh = b * G + hl;
  float2 ml0 = Ml[bh * 2048 + m];
  float2 ml1 = Ml[bhN * 2048 + bh * 2048 + m];
  float mm = fmaxf(ml0.x, ml1.x);
  float w0 = __expf(ml0.x - mm) * ml0.y;
  bool h1 = (ml1.y > 0.f);
  float w1 = h1 ? __expf(ml1.x - mm) * ml1.y : 0.f;
  float inv = 1.f / (w0 + w1);
  float a0 = w0 * inv, a1 = w1 * inv;
  bf16x8 v0 = *reinterpret_cast<const bf16x8*>(O0 + flat);
  bf16x8 out;
  if (h1) {
    bf16x8 v1 = *reinterpret_cast<const bf16x8*>(O1 + flat);
#pragma unroll
    for (int j = 0; j < 8; j++) out[j] = (__bf16)(a0 * (float)v0[j] + a1 * (float)v1[j]);
  } else {
#pragma unroll
    for (int j = 0; j < 8; j++) out[j] = (__bf16)(a0 * (float)v0[j]);
  }
  *reinterpret_cast<bf16x8*>(O0 + flat) = out;
}

// ---------------- output projection: 128x64 tile ----------------
__global__ __launch_bounds__(256) void out_gemm_k(
    const __bf16* __restrict__ A, const __bf16* __restrict__ Wo,
    const float* __restrict__ bias, float* __restrict__ Y, int G, int first) {
  const int AS = 512 * G;
  const int mbase = blockIdx.x * 128, nbase = blockIdx.y * 64;
  __shared__ alignas(16) __bf16 As[128 * 64];
  __shared__ alignas(16) __bf16 Bs[64 * 64];
  const int tid = threadIdx.x;
  const int lane = tid & 63, wid = tid >> 6;
  const int wr = wid >> 1, wc = wid & 1;
  const int l15 = lane & 15, l4 = lane >> 4;

  f32x4 acc[4][2];
#pragma unroll
  for (int i = 0; i < 4; i++)
#pragma unroll
    for (int j = 0; j < 2; j++) acc[i][j] = f32x4{0.f, 0.f, 0.f, 0.f};

  const int nkt = 8 * G;
  for (int kt = 0; kt < nkt; ++kt) {
    const int kb = kt * 64;
#pragma unroll
    for (int i = 0; i < 4; i++) {
      int chunk = i * 256 + tid;
      int row = chunk >> 3, col = (chunk & 7) * 8;
      g2l16(A + (size_t)(mbase + row) * AS + kb + col, As + (i * 256 + (tid & ~63)) * 8);
    }
#pragma unroll
    for (int i = 0; i < 2; i++) {
      int chunk = i * 256 + tid;
      int row = chunk >> 3, col = (chunk & 7) * 8;
      g2l16(Wo + (size_t)(nbase + row) * 4096 + kb + col, Bs + (i * 256 + (tid & ~63)) * 8);
    }
    __syncthreads();
#pragma unroll
    for (int kk = 0; kk < 2; ++kk) {
      bf16x8 a[4], b[2];
#pragma unroll
      for (int i = 0; i < 4; i++)
        a[i] = *reinterpret_cast<const bf16x8*>(As + (wr * 64 + i * 16 + l15) * 64 + kk * 32 + l4 * 8);
#pragma unroll
      for (int j = 0; j < 2; j++)
        b[j] = *reinterpret_cast<const bf16x8*>(Bs + (wc * 32 + j * 16 + l15) * 64 + kk * 32 + l4 * 8);
#pragma unroll
      for (int i = 0; i < 4; i++)
#pragma unroll
        for (int j = 0; j < 2; j++) acc[i][j] = MFMA16(a[i], b[j], acc[i][j]);
    }
    __syncthreads();
  }

#pragma unroll
  for (int i = 0; i < 4; i++) {
#pragma unroll
    for (int j = 0; j < 2; j++) {
      const int col = nbase + wc * 32 + j * 16 + l15;
#pragma unroll
      for (int r = 0; r < 4; r++) {
        const int row = mbase + wr * 64 + i * 16 + l4 * 4 + r;
        float prev = first ? bias[col] : Y[(size_t)row * 512 + col];
        Y[(size_t)row * 512 + col] = prev + acc[i][j][r];
      }
    }
  }
}

extern "C" void kernel_launch(void* const* d_in, const int* in_sizes, int n_in,
                              void* d_out, int out_size, void* d_ws, size_t ws_size,
                              hipStream_t stream) {
  (void)in_sizes; (void)n_in; (void)out_size;
  const float* x = (const float*)d_in[0];
  const float* wq = (const float*)d_in[1];
  const float* wk = (const float*)d_in[2];
  const float* wv = (const float*)d_in[3];
  const float* wo = (const float*)d_in[4];
  const float* bo = (const float*)d_in[5];
  float* y = (float*)d_out;

  char* base = (char*)d_ws;
  size_t off = 0;
  auto alloc = [&](size_t bytes) -> void* {
    void* p = base + off;
    off += (bytes + 255) & ~(size_t)255;
    return p;
  };
  __bf16* xb = (__bf16*)alloc((size_t)8192 * 512 * 2);
  __bf16* wqb = (__bf16*)alloc((size_t)8 * 512 * 512 * 2);
  __bf16* wkb = (__bf16*)alloc((size_t)8 * 512 * 512 * 2);
  __bf16* wvb = (__bf16*)alloc((size_t)8 * 512 * 512 * 2);
  __bf16* wob = (__bf16*)alloc((size_t)512 * 4096 * 2);
  float* ct = (float*)alloc((size_t)2048 * 256 * 4);
  float* st = (float*)alloc((size_t)2048 * 256 * 4);
  const size_t persist = off;

  int G = 0, lg = 0;
  for (int g = 8, l = 3; g >= 1; g >>= 1, --l) {
    size_t T = ((size_t)g * 4 * 2048 * 512 * 2 + 255) & ~(size_t)255;
    if (persist + 4 * T <= ws_size) { G = g; lg = l; break; }
  }
  if (G == 0) return;

  const int bhN = 4 * G;
  size_t T = ((size_t)G * 4 * 2048 * 512 * 2 + 255) & ~(size_t)255;
  size_t mlBytes = ((size_t)2 * bhN * 2048 * sizeof(float2) + 255) & ~(size_t)255;
  bool SPLIT = (G >= 2) && (persist + 5 * T + mlBytes <= ws_size);

  __bf16* Qb = (__bf16*)(base + persist);
  __bf16* Kb = (__bf16*)(base + persist + T);
  __bf16* VTb = (__bf16*)(base + persist + 2 * T);
  __bf16* Ob = (__bf16*)(base + persist + 3 * T);
  __bf16* O1b = SPLIT ? (__bf16*)(base + persist + 4 * T) : Ob;
  float2* Mlb = SPLIT ? (float2*)(base + persist + 5 * T) : (float2*)(base + persist);

  prep_k<<<14336, 256, 0, stream>>>(x, wq, wk, wv, wo, xb, wqb, wkb, wvb, wob, ct, st);

  const int n8 = bhN * 2048 * 64;
  for (int h0 = 0; h0 < 8; h0 += G) {
    qkv_gemm_k<<<dim3(64, 4, 3 * G), 256, 0, stream>>>(xb, wqb, wkb, wvb, ct, st,
                                                       Qb, Kb, VTb, G, lg, h0);
    if (SPLIT) {
      flashB_k<<<dim3(32 * bhN), 512, 0, stream>>>(Qb, Kb, VTb, Ob, O1b, Mlb, G, lg);
      merge_k<<<(n8 + 255) / 256, 256, 0, stream>>>(Ob, O1b, Mlb, G, lg, n8);
    } else {
      flash_attn_k<<<dim3(16, bhN), 512, 0, stream>>>(Qb, Kb, VTb, Ob, G, lg);
    }
    out_gemm_k<<<dim3(64, 8), 256, 0, stream>>>(Ob, wob + h0 * 512, bo, y, G, h0 == 0);
  }
}